// Round 1
// baseline (95795.435 us; speedup 1.0000x reference)
//
#include <hip/hip_runtime.h>
#include <stdint.h>

#define BB 64      // batch
#define SS 1024    // memory length
#define TT 511     // decode steps
#define EE 512     // embedding dim
#define UU 1024    // units (= M = V here)
#define G4 4096    // 4*U

// ---------- small helpers ----------
__device__ __forceinline__ float bf2f_lo(unsigned int u) {
    union { unsigned int i; float f; } w; w.i = u << 16; return w.f;
}
__device__ __forceinline__ float bf2f_hi(unsigned int u) {
    union { unsigned int i; float f; } w; w.i = u & 0xFFFF0000u; return w.f;
}
__device__ __forceinline__ unsigned short f2bf(float f) {
    union { float f; unsigned int i; } w; w.f = f;
    return (unsigned short)((w.i + 0x7FFFu + ((w.i >> 16) & 1u)) >> 16);
}
__device__ __forceinline__ float fast_tanh(float x) {
    float e = __expf(2.0f * x);
    return 1.0f - 2.0f / (e + 1.0f);
}
__device__ __forceinline__ float sigmoidf_(float x) {
    return 1.0f / (1.0f + __expf(-x));
}

// ---------- init: h=enc_h, c=enc_c, apart=0 ----------
__global__ void k_init(const float* __restrict__ enc_h, const float* __restrict__ enc_c,
                       float* __restrict__ h, float* __restrict__ c, float* __restrict__ apart)
{
    int idx = blockIdx.x * 256 + threadIdx.x;
    if (idx < BB * UU) { h[idx] = enc_h[idx]; c[idx] = enc_c[idx]; }
    for (int i = idx; i < 8 * BB * UU; i += (int)gridDim.x * 256) apart[i] = 0.f;
}

// ---------- fp32 -> bf16 copy of memory ----------
__global__ void k_cvt(const float4* __restrict__ src, ushort4* __restrict__ dst, int n4)
{
    int idx = blockIdx.x * 256 + threadIdx.x;
    for (int i = idx; i < n4; i += (int)gridDim.x * 256) {
        float4 f = src[i];
        ushort4 o;
        o.x = f2bf(f.x); o.y = f2bf(f.y); o.z = f2bf(f.z); o.w = f2bf(f.w);
        dst[i] = o;
    }
}

// ---------- keys = memory @ Wm, bf16 out.  [65536 x 1024] @ [1024 x 1024] ----------
__global__ __launch_bounds__(256) void k_keys(const float* __restrict__ A, const float* __restrict__ W,
                                              unsigned short* __restrict__ keys)
{
    __shared__ __align__(16) float As[32][68];
    __shared__ __align__(16) float Ws[32][72];
    const int tid = threadIdx.x;
    const int tx = tid & 15, ty = tid >> 4;
    const int r0 = blockIdx.y * 64;
    const int c0 = blockIdx.x * 64;
    float acc[4][4] = {};
    const int am = tid >> 2, akq = tid & 3;
    const int wc4 = (tid & 15) * 4, wk0 = tid >> 4;
    for (int k0 = 0; k0 < 1024; k0 += 32) {
        const float* p = A + (size_t)(r0 + am) * 1024 + k0 + 8 * akq;
        float4 x0 = *(const float4*)p;
        float4 x1 = *(const float4*)(p + 4);
        As[8*akq+0][am] = x0.x; As[8*akq+1][am] = x0.y; As[8*akq+2][am] = x0.z; As[8*akq+3][am] = x0.w;
        As[8*akq+4][am] = x1.x; As[8*akq+5][am] = x1.y; As[8*akq+6][am] = x1.z; As[8*akq+7][am] = x1.w;
        #pragma unroll
        for (int j = 0; j < 2; ++j) {
            const int kk = wk0 + 16 * j;
            *(float4*)&Ws[kk][wc4] = *(const float4*)&W[(size_t)(k0 + kk) * 1024 + c0 + wc4];
        }
        __syncthreads();
        #pragma unroll
        for (int kk = 0; kk < 32; ++kk) {
            float4 a4 = *(const float4*)&As[kk][4 * ty];
            float4 w4 = *(const float4*)&Ws[kk][4 * tx];
            const float aa[4] = {a4.x, a4.y, a4.z, a4.w};
            const float ww[4] = {w4.x, w4.y, w4.z, w4.w};
            #pragma unroll
            for (int i = 0; i < 4; ++i)
                #pragma unroll
                for (int j = 0; j < 4; ++j)
                    acc[i][j] += aa[i] * ww[j];
        }
        __syncthreads();
    }
    #pragma unroll
    for (int i = 0; i < 4; ++i)
        #pragma unroll
        for (int j = 0; j < 4; ++j)
            keys[(size_t)(r0 + 4*ty + i) * 1024 + c0 + 4*tx + j] = f2bf(acc[i][j]);
}

// ---------- generic small GEMM: Cpart[gy][64][N] = A[64 x Kc-slice] @ W[Kc-slice x N] ----------
#define MODE_PLAIN 0
#define MODE_CAT   1
#define MODE_HCTX  2
#define MODE_APART 3

template<int MODE>
__global__ __launch_bounds__(256) void g_small(
    const float* __restrict__ Aplain,
    const float* __restrict__ emb, const int* __restrict__ tokens, int t,
    const float* __restrict__ apart,
    const float* __restrict__ hbuf,
    const float* __restrict__ ctx, const float* __restrict__ denom,
    const float* __restrict__ W1, const float* __restrict__ W2, int wsplit,
    float* __restrict__ Cpart, int N, int K, int Kc)
{
    __shared__ __align__(16) float As[32][68];
    __shared__ __align__(16) float Ws[32][72];
    const int tid = threadIdx.x;
    const int tx = tid & 15, ty = tid >> 4;
    const int c0 = blockIdx.x * 64;
    const int gy = blockIdx.y;
    const int kbeg = gy * Kc;
    float acc[4][4] = {};
    const int am = tid >> 2, akq = tid & 3;
    const int wc4 = (tid & 15) * 4, wk0 = tid >> 4;

    for (int k0 = kbeg; k0 < kbeg + Kc; k0 += 32) {
        // ---- A tile (rows = batch 0..63, cols = k0..k0+31) ----
        {
            const int b  = am;
            const int kg = k0 + 8 * akq;     // 8 consecutive k's, never straddles a region
            float av[8];
            if (MODE == MODE_PLAIN) {
                const float* p = Aplain + (size_t)b * K + kg;
                float4 x0 = *(const float4*)p;
                float4 x1 = *(const float4*)(p + 4);
                av[0]=x0.x; av[1]=x0.y; av[2]=x0.z; av[3]=x0.w;
                av[4]=x1.x; av[5]=x1.y; av[6]=x1.z; av[7]=x1.w;
            } else if (MODE == MODE_CAT) {
                if (kg < EE) {
                    const int tok = tokens[b * TT + t];
                    const float* p = emb + (size_t)tok * EE + kg;
                    float4 x0 = *(const float4*)p;
                    float4 x1 = *(const float4*)(p + 4);
                    av[0]=x0.x; av[1]=x0.y; av[2]=x0.z; av[3]=x0.w;
                    av[4]=x1.x; av[5]=x1.y; av[6]=x1.z; av[7]=x1.w;
                } else if (kg < EE + UU) {
                    const int u = kg - EE;
                    #pragma unroll
                    for (int i = 0; i < 8; ++i) av[i] = 0.f;
                    #pragma unroll
                    for (int p8 = 0; p8 < 8; ++p8) {
                        const float* p = apart + (size_t)(p8 * BB + b) * UU + u;
                        float4 x0 = *(const float4*)p;
                        float4 x1 = *(const float4*)(p + 4);
                        av[0]+=x0.x; av[1]+=x0.y; av[2]+=x0.z; av[3]+=x0.w;
                        av[4]+=x1.x; av[5]+=x1.y; av[6]+=x1.z; av[7]+=x1.w;
                    }
                } else {
                    const int u = kg - (EE + UU);
                    const float* p = hbuf + (size_t)b * UU + u;
                    float4 x0 = *(const float4*)p;
                    float4 x1 = *(const float4*)(p + 4);
                    av[0]=x0.x; av[1]=x0.y; av[2]=x0.z; av[3]=x0.w;
                    av[4]=x1.x; av[5]=x1.y; av[6]=x1.z; av[7]=x1.w;
                }
            } else if (MODE == MODE_HCTX) {
                if (kg < UU) {
                    const float* p = hbuf + (size_t)b * UU + kg;
                    float4 x0 = *(const float4*)p;
                    float4 x1 = *(const float4*)(p + 4);
                    av[0]=x0.x; av[1]=x0.y; av[2]=x0.z; av[3]=x0.w;
                    av[4]=x1.x; av[5]=x1.y; av[6]=x1.z; av[7]=x1.w;
                } else {
                    const float rd = 1.0f / denom[b];
                    const float* p = ctx + (size_t)b * UU + (kg - UU);
                    float4 x0 = *(const float4*)p;
                    float4 x1 = *(const float4*)(p + 4);
                    av[0]=x0.x*rd; av[1]=x0.y*rd; av[2]=x0.z*rd; av[3]=x0.w*rd;
                    av[4]=x1.x*rd; av[5]=x1.y*rd; av[6]=x1.z*rd; av[7]=x1.w*rd;
                }
            } else { // MODE_APART : A = sum of 8 attention partials
                #pragma unroll
                for (int i = 0; i < 8; ++i) av[i] = 0.f;
                #pragma unroll
                for (int p8 = 0; p8 < 8; ++p8) {
                    const float* p = apart + (size_t)(p8 * BB + b) * UU + kg;
                    float4 x0 = *(const float4*)p;
                    float4 x1 = *(const float4*)(p + 4);
                    av[0]+=x0.x; av[1]+=x0.y; av[2]+=x0.z; av[3]+=x0.w;
                    av[4]+=x1.x; av[5]+=x1.y; av[6]+=x1.z; av[7]+=x1.w;
                }
            }
            #pragma unroll
            for (int i = 0; i < 8; ++i) As[8*akq + i][am] = av[i];
        }
        // ---- W tile ----
        #pragma unroll
        for (int j = 0; j < 2; ++j) {
            const int kk = wk0 + 16 * j;
            const int kg = k0 + kk;
            const float* Wp = (kg < wsplit) ? (W1 + (size_t)kg * N) : (W2 + (size_t)(kg - wsplit) * N);
            *(float4*)&Ws[kk][wc4] = *(const float4*)&Wp[c0 + wc4];
        }
        __syncthreads();
        #pragma unroll
        for (int kk = 0; kk < 32; ++kk) {
            float4 a4 = *(const float4*)&As[kk][4 * ty];
            float4 w4 = *(const float4*)&Ws[kk][4 * tx];
            const float aa[4] = {a4.x, a4.y, a4.z, a4.w};
            const float ww[4] = {w4.x, w4.y, w4.z, w4.w};
            #pragma unroll
            for (int i = 0; i < 4; ++i)
                #pragma unroll
                for (int j = 0; j < 4; ++j)
                    acc[i][j] += aa[i] * ww[j];
        }
        __syncthreads();
    }
    #pragma unroll
    for (int i = 0; i < 4; ++i)
        #pragma unroll
        for (int j = 0; j < 4; ++j)
            Cpart[((size_t)gy * BB + 4*ty + i) * N + c0 + 4*tx + j] = acc[i][j];
}

// ---------- LSTM gates: z = sum(zpart) + bias -> h,c (in-place); zero denom ----------
__global__ void k_gates(const float* __restrict__ zpart, const float* __restrict__ bias,
                        float* __restrict__ h, float* __restrict__ c, float* __restrict__ denom)
{
    const int idx = blockIdx.x * 256 + threadIdx.x;  // 65536
    const int b = idx >> 10, u = idx & 1023;
    float zi = 0.f, zf = 0.f, zg = 0.f, zo = 0.f;
    #pragma unroll
    for (int p = 0; p < 4; ++p) {
        const float* zp = zpart + (size_t)p * BB * G4 + (size_t)b * G4;
        zi += zp[u]; zf += zp[u + 1024]; zg += zp[u + 2048]; zo += zp[u + 3072];
    }
    const float i_ = sigmoidf_(zi + bias[u]);
    const float f_ = sigmoidf_(zf + bias[u + 1024]);
    const float g_ = fast_tanh(zg + bias[u + 2048]);
    const float o_ = sigmoidf_(zo + bias[u + 3072]);
    const float cn = f_ * c[idx] + i_ * g_;
    c[idx] = cn;
    h[idx] = o_ * fast_tanh(cn);
    if (idx < BB) denom[idx] = 0.f;
}

// ---------- scores: e = exp(v . tanh(q + keys)); denom += sum(e); zero ctx ----------
__global__ __launch_bounds__(256) void k_score(const unsigned short* __restrict__ keys,
        const float* __restrict__ qpart, const float* __restrict__ vvec,
        float* __restrict__ escore, float* __restrict__ denom, float* __restrict__ ctx)
{
    __shared__ float qs[1024];
    __shared__ float vs[1024];
    __shared__ float lsum;
    const int tid = threadIdx.x;
    const int bid = blockIdx.x;             // 2048 = 64 b * 32 chunks
    const int b = bid >> 5, chunk = bid & 31;
    if (chunk == 0) {
        for (int i = tid; i < UU; i += 256) ctx[(size_t)b * UU + i] = 0.f;
    }
    for (int i = tid; i < UU; i += 256) {
        float q = 0.f;
        #pragma unroll
        for (int p = 0; p < 8; ++p) q += qpart[(size_t)(p * BB + b) * UU + i];
        qs[i] = q;
        vs[i] = vvec[i];
    }
    if (tid == 0) lsum = 0.f;
    __syncthreads();
    const int lane = tid & 63;
    const int w = tid >> 6;
    float qv[16], vv[16];
    #pragma unroll
    for (int j = 0; j < 2; ++j)
        #pragma unroll
        for (int i = 0; i < 8; ++i) {
            qv[8*j + i] = qs[8*lane + 512*j + i];
            vv[8*j + i] = vs[8*lane + 512*j + i];
        }
    const int s0 = chunk * 32 + w * 8;
    float wsum = 0.f;
    for (int it = 0; it < 8; ++it) {
        const int s = s0 + it;
        const unsigned short* kp = keys + ((size_t)(b * SS + s) << 10);
        float acc = 0.f;
        #pragma unroll
        for (int j = 0; j < 2; ++j) {
            uint4 raw = *(const uint4*)&kp[8*lane + 512*j];
            float kx[8];
            kx[0] = bf2f_lo(raw.x); kx[1] = bf2f_hi(raw.x);
            kx[2] = bf2f_lo(raw.y); kx[3] = bf2f_hi(raw.y);
            kx[4] = bf2f_lo(raw.z); kx[5] = bf2f_hi(raw.z);
            kx[6] = bf2f_lo(raw.w); kx[7] = bf2f_hi(raw.w);
            #pragma unroll
            for (int i = 0; i < 8; ++i)
                acc += vv[8*j + i] * fast_tanh(qv[8*j + i] + kx[i]);
        }
        #pragma unroll
        for (int m = 32; m >= 1; m >>= 1) acc += __shfl_xor(acc, m, 64);
        if (lane == 0) {
            const float es = __expf(acc);
            escore[(size_t)b * SS + s] = es;
            wsum += es;
        }
    }
    if (lane == 0) atomicAdd(&lsum, wsum);
    __syncthreads();
    if (tid == 0) atomicAdd(&denom[b], lsum);
}

// ---------- ctx[b][m] += sum_s escore[b][s] * memory[b][s][m] ----------
template<int BF16>
__global__ __launch_bounds__(256) void k_ctx(const void* __restrict__ mem,
        const float* __restrict__ escore, float* __restrict__ ctx)
{
    __shared__ float es[64];
    const int tid = threadIdx.x;
    const int bid = blockIdx.x;            // 1024 = 64 b * 16 chunks
    const int b = bid >> 4, chunk = bid & 15;
    const int s0 = chunk * 64;
    if (tid < 64) es[tid] = escore[(size_t)b * SS + s0 + tid];
    __syncthreads();
    float a0 = 0.f, a1 = 0.f, a2 = 0.f, a3 = 0.f;
    const int m0 = tid * 4;
    for (int i = 0; i < 64; ++i) {
        const float wgt = es[i];
        const size_t base = ((size_t)(b * SS + s0 + i) << 10) + m0;
        if (BF16) {
            const unsigned short* mp = (const unsigned short*)mem + base;
            uint2 u = *(const uint2*)mp;
            a0 += wgt * bf2f_lo(u.x); a1 += wgt * bf2f_hi(u.x);
            a2 += wgt * bf2f_lo(u.y); a3 += wgt * bf2f_hi(u.y);
        } else {
            const float4 f = *(const float4*)((const float*)mem + base);
            a0 += wgt * f.x; a1 += wgt * f.y; a2 += wgt * f.z; a3 += wgt * f.w;
        }
    }
    float* cp = ctx + (size_t)b * UU + m0;
    atomicAdd(cp + 0, a0);
    atomicAdd(cp + 1, a1);
    atomicAdd(cp + 2, a2);
    atomicAdd(cp + 3, a3);
}

// ---------- out[b][t][v] = sum(opart) + bfc ----------
__global__ void k_red_out(const float* __restrict__ opart, const float* __restrict__ bfc,
                          float* __restrict__ out, int t)
{
    const int idx = blockIdx.x * 256 + threadIdx.x;  // 65536
    const int b = idx >> 10, v = idx & 1023;
    float a = bfc[v];
    #pragma unroll
    for (int p = 0; p < 8; ++p) a += opart[(size_t)(p * BB + b) * UU + v];
    out[((size_t)b * TT + t) * 1024 + v] = a;
}

// ---------- host ----------
extern "C" void kernel_launch(void* const* d_in, const int* in_sizes, int n_in,
                              void* d_out, int out_size, void* d_ws, size_t ws_size,
                              hipStream_t stream)
{
    const int*   tokens = (const int*)d_in[0];
    const float* memory = (const float*)d_in[1];
    const float* enc_h  = (const float*)d_in[2];
    const float* enc_c  = (const float*)d_in[3];
    const float* emb    = (const float*)d_in[4];
    const float* Wk     = (const float*)d_in[5];
    const float* Wr     = (const float*)d_in[6];
    const float* bias   = (const float*)d_in[7];
    const float* Wm     = (const float*)d_in[8];
    const float* Wq     = (const float*)d_in[9];
    const float* vvec   = (const float*)d_in[10];
    const float* Wa     = (const float*)d_in[11];
    const float* Wfc    = (const float*)d_in[12];
    const float* bfc    = (const float*)d_in[13];
    float* out = (float*)d_out;

    char* ws = (char*)d_ws;
    size_t off = 0;
    auto take = [&](size_t bytes) -> char* {
        char* p = ws + off;
        off = (off + bytes + 255) & ~(size_t)255;
        return p;
    };
    unsigned short* keys  = (unsigned short*)take((size_t)BB * SS * UU * 2);  // 134 MB
    float* zpart  = (float*)take((size_t)4 * BB * G4 * 4);                    // 4 MB
    float* qpart  = (float*)take((size_t)8 * BB * UU * 4);                    // 2 MB
    float* apart  = (float*)take((size_t)8 * BB * UU * 4);                    // 2 MB
    float* opart  = (float*)take((size_t)8 * BB * UU * 4);                    // 2 MB
    float* h      = (float*)take((size_t)BB * UU * 4);
    float* c      = (float*)take((size_t)BB * UU * 4);
    float* escore = (float*)take((size_t)BB * SS * 4);
    float* denom  = (float*)take(256);
    float* ctx    = (float*)take((size_t)BB * UU * 4);
    const bool planA = (off + (size_t)BB * SS * UU * 2) <= ws_size;
    unsigned short* membf = planA ? (unsigned short*)take((size_t)BB * SS * UU * 2) : nullptr;

    k_init<<<dim3(2048), dim3(256), 0, stream>>>(enc_h, enc_c, h, c, apart);
    if (planA)
        k_cvt<<<dim3(4096), dim3(256), 0, stream>>>((const float4*)memory, (ushort4*)membf,
                                                    (BB * SS * UU) / 4);
    k_keys<<<dim3(16, 1024), dim3(256), 0, stream>>>(memory, Wm, keys);

    const int HUGE_SPLIT = 1 << 30;
    for (int t = 0; t < TT; ++t) {
        // z = [emb, attn] @ Wk + h @ Wr   (4 K-split partials)
        g_small<MODE_CAT><<<dim3(64, 4), dim3(256), 0, stream>>>(
            nullptr, emb, tokens, t, apart, h, nullptr, nullptr,
            Wk, Wr, EE + UU, zpart, 4096, 2560, 640);
        // gates -> h,c (in place), zero denom
        k_gates<<<dim3(256), dim3(256), 0, stream>>>(zpart, bias, h, c, denom);
        // q = h @ Wq (8 partials)
        g_small<MODE_PLAIN><<<dim3(16, 8), dim3(256), 0, stream>>>(
            h, nullptr, nullptr, 0, nullptr, nullptr, nullptr, nullptr,
            Wq, Wq, HUGE_SPLIT, qpart, 1024, 1024, 128);
        // scores + denom (+ zero ctx)
        k_score<<<dim3(2048), dim3(256), 0, stream>>>(keys, qpart, vvec, escore, denom, ctx);
        // ctx accumulation
        if (planA)
            k_ctx<1><<<dim3(1024), dim3(256), 0, stream>>>(membf, escore, ctx);
        else
            k_ctx<0><<<dim3(1024), dim3(256), 0, stream>>>(memory, escore, ctx);
        // attn = [h, ctx/denom] @ Wa (8 partials, written to apart)
        g_small<MODE_HCTX><<<dim3(16, 8), dim3(256), 0, stream>>>(
            nullptr, nullptr, nullptr, 0, nullptr, h, ctx, denom,
            Wa, Wa, HUGE_SPLIT, apart, 1024, 2048, 256);
        // out = attn @ Wfc (8 partials)
        g_small<MODE_APART><<<dim3(16, 8), dim3(256), 0, stream>>>(
            nullptr, nullptr, nullptr, 0, apart, nullptr, nullptr, nullptr,
            Wfc, Wfc, HUGE_SPLIT, opart, 1024, 1024, 128);
        // reduce + bias -> d_out[:, t, :]
        k_red_out<<<dim3(256), dim3(256), 0, stream>>>(opart, bfc, out, t);
    }
}

// Round 2
// 93181.195 us; speedup vs baseline: 1.0281x; 1.0281x over previous
//
#include <hip/hip_runtime.h>
#include <stdint.h>

#define BB 64      // batch
#define SS 1024    // memory length
#define TT 511     // decode steps
#define EE 512     // embedding dim
#define UU 1024    // units (= M = V here)
#define G4 4096    // 4*U

// ---------- small helpers ----------
__device__ __forceinline__ float bf2f_lo(unsigned int u) {
    union { unsigned int i; float f; } w; w.i = u << 16; return w.f;
}
__device__ __forceinline__ float bf2f_hi(unsigned int u) {
    union { unsigned int i; float f; } w; w.i = u & 0xFFFF0000u; return w.f;
}
__device__ __forceinline__ unsigned short f2bf(float f) {
    union { float f; unsigned int i; } w; w.f = f;
    return (unsigned short)((w.i + 0x7FFFu + ((w.i >> 16) & 1u)) >> 16);
}
__device__ __forceinline__ float fast_tanh(float x) {
    float e = __expf(2.0f * x);
    return 1.0f - 2.0f / (e + 1.0f);
}
__device__ __forceinline__ float sigmoidf_(float x) {
    return 1.0f / (1.0f + __expf(-x));
}

// ---------- init: h=enc_h, c=enc_c, attnbuf=0 ----------
__global__ void k_init(const float* __restrict__ enc_h, const float* __restrict__ enc_c,
                       float* __restrict__ h, float* __restrict__ c, float* __restrict__ attnb)
{
    int idx = blockIdx.x * 256 + threadIdx.x;   // 65536
    h[idx] = enc_h[idx];
    c[idx] = enc_c[idx];
    attnb[idx] = 0.f;
}

// ---------- d_out pre-fill with bias (out-GEMM atomically accumulates into it) ----------
__global__ void k_init_out(const float4* __restrict__ bfc4, float4* __restrict__ out4, int n4)
{
    int idx = blockIdx.x * 256 + threadIdx.x;
    for (int i = idx; i < n4; i += (int)gridDim.x * 256)
        out4[i] = bfc4[i & 255];
}

// ---------- fp32 -> bf16 copy of memory ----------
__global__ void k_cvt(const float4* __restrict__ src, ushort4* __restrict__ dst, int n4)
{
    int idx = blockIdx.x * 256 + threadIdx.x;
    for (int i = idx; i < n4; i += (int)gridDim.x * 256) {
        float4 f = src[i];
        ushort4 o;
        o.x = f2bf(f.x); o.y = f2bf(f.y); o.z = f2bf(f.z); o.w = f2bf(f.w);
        dst[i] = o;
    }
}

// ---------- keys = memory @ Wm, bf16 out.  [65536 x 1024] @ [1024 x 1024] ----------
__global__ __launch_bounds__(256) void k_keys(const float* __restrict__ A, const float* __restrict__ W,
                                              unsigned short* __restrict__ keys)
{
    __shared__ __align__(16) float As[32][68];
    __shared__ __align__(16) float Ws[32][72];
    const int tid = threadIdx.x;
    const int tx = tid & 15, ty = tid >> 4;
    const int r0 = blockIdx.y * 64;
    const int c0 = blockIdx.x * 64;
    float acc[4][4] = {};
    const int am = tid >> 2, akq = tid & 3;
    const int wc4 = (tid & 15) * 4, wk0 = tid >> 4;
    for (int k0 = 0; k0 < 1024; k0 += 32) {
        const float* p = A + (size_t)(r0 + am) * 1024 + k0 + 8 * akq;
        float4 x0 = *(const float4*)p;
        float4 x1 = *(const float4*)(p + 4);
        As[8*akq+0][am] = x0.x; As[8*akq+1][am] = x0.y; As[8*akq+2][am] = x0.z; As[8*akq+3][am] = x0.w;
        As[8*akq+4][am] = x1.x; As[8*akq+5][am] = x1.y; As[8*akq+6][am] = x1.z; As[8*akq+7][am] = x1.w;
        #pragma unroll
        for (int j = 0; j < 2; ++j) {
            const int kk = wk0 + 16 * j;
            *(float4*)&Ws[kk][wc4] = *(const float4*)&W[(size_t)(k0 + kk) * 1024 + c0 + wc4];
        }
        __syncthreads();
        #pragma unroll
        for (int kk = 0; kk < 32; ++kk) {
            float4 a4 = *(const float4*)&As[kk][4 * ty];
            float4 w4 = *(const float4*)&Ws[kk][4 * tx];
            const float aa[4] = {a4.x, a4.y, a4.z, a4.w};
            const float ww[4] = {w4.x, w4.y, w4.z, w4.w};
            #pragma unroll
            for (int i = 0; i < 4; ++i)
                #pragma unroll
                for (int j = 0; j < 4; ++j)
                    acc[i][j] += aa[i] * ww[j];
        }
        __syncthreads();
    }
    #pragma unroll
    for (int i = 0; i < 4; ++i)
        #pragma unroll
        for (int j = 0; j < 4; ++j)
            keys[(size_t)(r0 + 4*ty + i) * 1024 + c0 + 4*tx + j] = f2bf(acc[i][j]);
}

// ---------- generic small GEMM on 64 batch rows ----------
// MODE_PLAIN: A = Aplain[64 x K]
// MODE_CAT:   A = [emb(tok) 512 | attnb 1024 | h 1024], K=2560
// MODE_HCTX:  A = [h 1024 | ctx/denom 1024], K=2048
// ATOMIC=0: write partials Cpart[gy][64][N]. ATOMIC=1: atomicAdd C[row*rs+col].
#define MODE_PLAIN 0
#define MODE_CAT   1
#define MODE_HCTX  2

template<int MODE, int ATOMIC>
__global__ __launch_bounds__(256) void g_small(
    const float* __restrict__ Aplain,
    const float* __restrict__ emb, const int* __restrict__ tokens, int t,
    const float* __restrict__ attnb,
    const float* __restrict__ hbuf,
    const float* __restrict__ ctx, const float* __restrict__ denom,
    const float* __restrict__ W1, const float* __restrict__ W2, int wsplit,
    float* __restrict__ C, int rs, int N, int K, int Kc)
{
    __shared__ __align__(16) float As[32][68];
    __shared__ __align__(16) float Ws[32][72];
    const int tid = threadIdx.x;
    const int tx = tid & 15, ty = tid >> 4;
    const int c0 = blockIdx.x * 64;
    const int gy = blockIdx.y;
    const int kbeg = gy * Kc;
    float acc[4][4] = {};
    const int am = tid >> 2, akq = tid & 3;
    const int wc4 = (tid & 15) * 4, wk0 = tid >> 4;
    int tok = 0; float rd = 0.f;
    if (MODE == MODE_CAT)  tok = tokens[am * TT + t];
    if (MODE == MODE_HCTX) rd = 1.0f / denom[am];

    for (int k0 = kbeg; k0 < kbeg + Kc; k0 += 32) {
        // ---- A tile: rows = batch, cols = k0..k0+31; 8 consecutive k per lane-group ----
        {
            const int kg = k0 + 8 * akq;
            const float* p;
            float scale = 1.0f;
            if (MODE == MODE_PLAIN) {
                p = Aplain + (size_t)am * K + kg;
            } else if (MODE == MODE_CAT) {
                if (kg < EE)           p = emb   + (size_t)tok * EE + kg;
                else if (kg < EE + UU) p = attnb + (size_t)am * UU + (kg - EE);
                else                   p = hbuf  + (size_t)am * UU + (kg - EE - UU);
            } else { // MODE_HCTX
                if (kg < UU)           p = hbuf  + (size_t)am * UU + kg;
                else { p = ctx + (size_t)am * UU + (kg - UU); scale = rd; }
            }
            float4 x0 = *(const float4*)p;
            float4 x1 = *(const float4*)(p + 4);
            As[8*akq+0][am] = x0.x*scale; As[8*akq+1][am] = x0.y*scale;
            As[8*akq+2][am] = x0.z*scale; As[8*akq+3][am] = x0.w*scale;
            As[8*akq+4][am] = x1.x*scale; As[8*akq+5][am] = x1.y*scale;
            As[8*akq+6][am] = x1.z*scale; As[8*akq+7][am] = x1.w*scale;
        }
        // ---- W tile ----
        #pragma unroll
        for (int j = 0; j < 2; ++j) {
            const int kk = wk0 + 16 * j;
            const int kg = k0 + kk;
            const float* Wp = (kg < wsplit) ? (W1 + (size_t)kg * N) : (W2 + (size_t)(kg - wsplit) * N);
            *(float4*)&Ws[kk][wc4] = *(const float4*)&Wp[c0 + wc4];
        }
        __syncthreads();
        #pragma unroll
        for (int kk = 0; kk < 32; ++kk) {
            float4 a4 = *(const float4*)&As[kk][4 * ty];
            float4 w4 = *(const float4*)&Ws[kk][4 * tx];
            const float aa[4] = {a4.x, a4.y, a4.z, a4.w};
            const float ww[4] = {w4.x, w4.y, w4.z, w4.w};
            #pragma unroll
            for (int i = 0; i < 4; ++i)
                #pragma unroll
                for (int j = 0; j < 4; ++j)
                    acc[i][j] += aa[i] * ww[j];
        }
        __syncthreads();
    }
    #pragma unroll
    for (int i = 0; i < 4; ++i)
        #pragma unroll
        for (int j = 0; j < 4; ++j) {
            const int row = 4*ty + i, col = c0 + 4*tx + j;
            if (ATOMIC) atomicAdd(&C[(size_t)row * rs + col], acc[i][j]);
            else        C[((size_t)gy * BB + row) * N + col] = acc[i][j];
        }
}

// ---------- LSTM gates: z = sum(zpart[8]) + bias -> h,c; zero denom/ctx/qbuf/attnb ----------
__global__ void k_gates(const float* __restrict__ zpart, const float* __restrict__ bias,
                        float* __restrict__ h, float* __restrict__ c, float* __restrict__ denom,
                        float* __restrict__ ctx, float* __restrict__ qbuf, float* __restrict__ attnb)
{
    const int idx = blockIdx.x * 256 + threadIdx.x;  // 65536
    const int b = idx >> 10, u = idx & 1023;
    float zi = 0.f, zf = 0.f, zg = 0.f, zo = 0.f;
    #pragma unroll
    for (int p = 0; p < 8; ++p) {
        const float* zp = zpart + ((size_t)p * BB + b) * G4;
        zi += zp[u]; zf += zp[u + 1024]; zg += zp[u + 2048]; zo += zp[u + 3072];
    }
    const float i_ = sigmoidf_(zi + bias[u]);
    const float f_ = sigmoidf_(zf + bias[u + 1024]);
    const float g_ = fast_tanh(zg + bias[u + 2048]);
    const float o_ = sigmoidf_(zo + bias[u + 3072]);
    const float cn = f_ * c[idx] + i_ * g_;
    c[idx] = cn;
    h[idx] = o_ * fast_tanh(cn);
    ctx[idx] = 0.f;
    qbuf[idx] = 0.f;
    attnb[idx] = 0.f;
    if (idx < BB) denom[idx] = 0.f;
}

// ---------- fused attention sweep: scores + denom + unnormalized ctx ----------
template<int BF16>
__global__ __launch_bounds__(256) void k_attn(const unsigned short* __restrict__ keys,
        const void* __restrict__ mem, const float* __restrict__ qbuf,
        const float* __restrict__ vvec, float* __restrict__ denom, float* __restrict__ ctx)
{
    __shared__ float qs[1024];
    __shared__ float vs[1024];
    __shared__ float es[64];
    const int tid = threadIdx.x;
    const int bid = blockIdx.x;             // 1024 = 64 b * 16 chunks of 64 s
    const int b = bid >> 4, chunk = bid & 15;
    const int s0 = chunk * 64;
    for (int i = tid; i < UU; i += 256) {
        qs[i] = qbuf[(size_t)b * UU + i];
        vs[i] = vvec[i];
    }
    __syncthreads();
    const int lane = tid & 63;
    const int w = tid >> 6;
    float qv[16], vv[16];
    #pragma unroll
    for (int j = 0; j < 2; ++j)
        #pragma unroll
        for (int i = 0; i < 8; ++i) {
            qv[8*j + i] = qs[8*lane + 512*j + i];
            vv[8*j + i] = vs[8*lane + 512*j + i];
        }
    // phase 1: e-scores for this block's 64 s-rows (16 per wave)
    float wsum = 0.f;
    for (int it = 0; it < 16; ++it) {
        const int sl = w * 16 + it;
        const unsigned short* kp = keys + ((size_t)(b * SS + s0 + sl) << 10);
        float acc = 0.f;
        #pragma unroll
        for (int j = 0; j < 2; ++j) {
            uint4 raw = *(const uint4*)&kp[8*lane + 512*j];
            float kx[8];
            kx[0] = bf2f_lo(raw.x); kx[1] = bf2f_hi(raw.x);
            kx[2] = bf2f_lo(raw.y); kx[3] = bf2f_hi(raw.y);
            kx[4] = bf2f_lo(raw.z); kx[5] = bf2f_hi(raw.z);
            kx[6] = bf2f_lo(raw.w); kx[7] = bf2f_hi(raw.w);
            #pragma unroll
            for (int i = 0; i < 8; ++i)
                acc += vv[8*j + i] * fast_tanh(qv[8*j + i] + kx[i]);
        }
        #pragma unroll
        for (int m = 32; m >= 1; m >>= 1) acc += __shfl_xor(acc, m, 64);
        if (lane == 0) {
            const float e = __expf(acc);
            es[sl] = e;
            wsum += e;
        }
    }
    if (lane == 0) atomicAdd(&denom[b], wsum);
    __syncthreads();
    // phase 2: ctx[b][m] += sum_s e[s] * memory[b][s][m]
    float a0 = 0.f, a1 = 0.f, a2 = 0.f, a3 = 0.f;
    const int m0 = tid * 4;
    #pragma unroll 8
    for (int i = 0; i < 64; ++i) {
        const float wgt = es[i];
        const size_t base = ((size_t)(b * SS + s0 + i) << 10) + m0;
        if (BF16) {
            uint2 u = *(const uint2*)((const unsigned short*)mem + base);
            a0 += wgt * bf2f_lo(u.x); a1 += wgt * bf2f_hi(u.x);
            a2 += wgt * bf2f_lo(u.y); a3 += wgt * bf2f_hi(u.y);
        } else {
            const float4 f = *(const float4*)((const float*)mem + base);
            a0 += wgt * f.x; a1 += wgt * f.y; a2 += wgt * f.z; a3 += wgt * f.w;
        }
    }
    float* cp = ctx + (size_t)b * UU + m0;
    atomicAdd(cp + 0, a0);
    atomicAdd(cp + 1, a1);
    atomicAdd(cp + 2, a2);
    atomicAdd(cp + 3, a3);
}

// ---------- host ----------
extern "C" void kernel_launch(void* const* d_in, const int* in_sizes, int n_in,
                              void* d_out, int out_size, void* d_ws, size_t ws_size,
                              hipStream_t stream)
{
    const int*   tokens = (const int*)d_in[0];
    const float* memory = (const float*)d_in[1];
    const float* enc_h  = (const float*)d_in[2];
    const float* enc_c  = (const float*)d_in[3];
    const float* emb    = (const float*)d_in[4];
    const float* Wk     = (const float*)d_in[5];
    const float* Wr     = (const float*)d_in[6];
    const float* bias   = (const float*)d_in[7];
    const float* Wm     = (const float*)d_in[8];
    const float* Wq     = (const float*)d_in[9];
    const float* vvec   = (const float*)d_in[10];
    const float* Wa     = (const float*)d_in[11];
    const float* Wfc    = (const float*)d_in[12];
    const float* bfc    = (const float*)d_in[13];
    float* out = (float*)d_out;

    char* ws = (char*)d_ws;
    size_t off = 0;
    auto take = [&](size_t bytes) -> char* {
        char* p = ws + off;
        off = (off + bytes + 255) & ~(size_t)255;
        return p;
    };
    unsigned short* keys  = (unsigned short*)take((size_t)BB * SS * UU * 2);  // 134 MB
    float* zpart  = (float*)take((size_t)8 * BB * G4 * 4);                    // 8 MB
    float* qbuf   = (float*)take((size_t)BB * UU * 4);
    float* attnb  = (float*)take((size_t)BB * UU * 4);
    float* h      = (float*)take((size_t)BB * UU * 4);
    float* c      = (float*)take((size_t)BB * UU * 4);
    float* denom  = (float*)take(256);
    float* ctx    = (float*)take((size_t)BB * UU * 4);
    const bool planA = (off + (size_t)BB * SS * UU * 2) <= ws_size;
    unsigned short* membf = planA ? (unsigned short*)take((size_t)BB * SS * UU * 2) : nullptr;

    k_init<<<dim3(256), dim3(256), 0, stream>>>(enc_h, enc_c, h, c, attnb);
    k_init_out<<<dim3(2048), dim3(256), 0, stream>>>((const float4*)bfc, (float4*)out,
                                                     (BB * TT * 1024) / 4);
    if (planA)
        k_cvt<<<dim3(4096), dim3(256), 0, stream>>>((const float4*)memory, (ushort4*)membf,
                                                    (BB * SS * UU) / 4);
    k_keys<<<dim3(16, 1024), dim3(256), 0, stream>>>(memory, Wm, keys);

    const int HUGE_SPLIT = 1 << 30;
    for (int t = 0; t < TT; ++t) {
        // z = [emb, attn] @ Wk + h @ Wr -> 8 K-split partials
        g_small<MODE_CAT, 0><<<dim3(64, 8), dim3(256), 0, stream>>>(
            nullptr, emb, tokens, t, attnb, h, nullptr, nullptr,
            Wk, Wr, EE + UU, zpart, 0, 4096, 2560, 320);
        // gates -> h,c; zero denom/ctx/qbuf/attnb
        k_gates<<<dim3(256), dim3(256), 0, stream>>>(zpart, bias, h, c, denom, ctx, qbuf, attnb);
        // q = h @ Wq  (atomic accumulate)
        g_small<MODE_PLAIN, 1><<<dim3(16, 8), dim3(256), 0, stream>>>(
            h, nullptr, nullptr, 0, nullptr, nullptr, nullptr, nullptr,
            Wq, Wq, HUGE_SPLIT, qbuf, 1024, 1024, 1024, 128);
        // fused scores + denom + unnormalized ctx
        if (planA)
            k_attn<1><<<dim3(1024), dim3(256), 0, stream>>>(keys, membf, qbuf, vvec, denom, ctx);
        else
            k_attn<0><<<dim3(1024), dim3(256), 0, stream>>>(keys, memory, qbuf, vvec, denom, ctx);
        // attn = [h, ctx/denom] @ Wa  (atomic accumulate)
        g_small<MODE_HCTX, 1><<<dim3(16, 8), dim3(256), 0, stream>>>(
            nullptr, nullptr, nullptr, 0, nullptr, h, ctx, denom,
            Wa, Wa, HUGE_SPLIT, attnb, 1024, 1024, 2048, 256);
        // out[:, t, :] += attn @ Wfc  (atomic accumulate into bias-prefilled d_out)
        g_small<MODE_PLAIN, 1><<<dim3(16, 8), dim3(256), 0, stream>>>(
            attnb, nullptr, nullptr, 0, nullptr, nullptr, nullptr, nullptr,
            Wfc, Wfc, HUGE_SPLIT, out + (size_t)t * 1024, TT * 1024, 1024, 1024, 128);
    }
}